// Round 3
// baseline (1505.384 us; speedup 1.0000x reference)
//
#include <hip/hip_runtime.h>

#define NN 10000
#define BB 32
#define EE 40000
#define HH 4
#define DD 10
#define TT 10
#define NEG 0.2f

#define NB   (NN*BB)          // 320000
#define NBT  (NN*BB*TT)       // 3200000

// ---------------- extract mu/sigma + regression heads ----------------
__global__ void extract_kernel(const float* __restrict__ x,
                               const float* __restrict__ wmu, const float* __restrict__ bmu,
                               const float* __restrict__ wsg, const float* __restrict__ bsg,
                               float* __restrict__ mu, float* __restrict__ sg,
                               float* __restrict__ regmu, float* __restrict__ regsg) {
    int i = blockIdx.x * blockDim.x + threadIdx.x;   // over N*B
    if (i >= NB) return;
    int n = i / BB, b = i % BB;
    float smu = 0.f, ssg = 0.f;
    float muv[TT], sgv[TT];
#pragma unroll
    for (int t = 0; t < TT; t++) {
        size_t xi = (((size_t)t * NN + n) * BB + b) * 3;
        float m = x[xi], s = x[xi + 1];
        muv[t] = m; sgv[t] = s;
        smu += m * wmu[t];
        ssg += s * wsg[t];
    }
#pragma unroll
    for (int t = 0; t < TT; t++) {
        mu[(size_t)i * TT + t] = muv[t];
        sg[(size_t)i * TT + t] = sgv[t];
    }
    regmu[i] = smu + bmu[0];
    regsg[i] = ssg + bsg[0];
}

// ---------------- CSR build ----------------
__global__ void deg_kernel(const int* __restrict__ dst, int* __restrict__ deg) {
    int e = blockIdx.x * blockDim.x + threadIdx.x;
    if (e < EE) atomicAdd(&deg[dst[e]], 1);
}

__global__ void scan_kernel(const int* __restrict__ deg, int* __restrict__ off) {
    __shared__ int sm[1024];
    __shared__ int carry_s;
    if (threadIdx.x == 0) { carry_s = 0; off[0] = 0; }
    __syncthreads();
    for (int base = 0; base < NN; base += 1024) {
        int i = base + (int)threadIdx.x;
        int v = (i < NN) ? deg[i] : 0;
        sm[threadIdx.x] = v;
        __syncthreads();
        for (int s = 1; s < 1024; s <<= 1) {
            int t = (threadIdx.x >= (unsigned)s) ? sm[threadIdx.x - s] : 0;
            __syncthreads();
            sm[threadIdx.x] += t;
            __syncthreads();
        }
        if (i < NN) off[i + 1] = carry_s + sm[threadIdx.x];
        __syncthreads();
        if (threadIdx.x == 0) carry_s += sm[1023];
        __syncthreads();
    }
}

__global__ void fill_kernel(const int* __restrict__ src, const int* __restrict__ dst,
                            const int* __restrict__ off, int* __restrict__ cursor,
                            int* __restrict__ csr_src) {
    int e = blockIdx.x * blockDim.x + threadIdx.x;
    if (e < EE) {
        int d = dst[e];
        int p = atomicAdd(&cursor[d], 1);
        csr_src[off[d] + p] = src[e];
    }
}

// ---------------- precompute vl/vr for all 8 GATs ----------------
// vbuf layout: 8 slots of [vl(40) | vr(40)];
// slot g: which = g&3 in {mu_p, sg_p, mu_r, sg_r}, layer = g>>2
__global__ void vpre_kernel(const float* __restrict__ fc0, const float* __restrict__ al0, const float* __restrict__ ar0,
                            const float* __restrict__ fc1, const float* __restrict__ al1, const float* __restrict__ ar1,
                            const float* __restrict__ fc2, const float* __restrict__ al2, const float* __restrict__ ar2,
                            const float* __restrict__ fc3, const float* __restrict__ al3, const float* __restrict__ ar3,
                            float* __restrict__ vbuf) {
    int j = threadIdx.x;                 // 0..319
    if (j >= 320) return;
    int g = j / 40, r = j % 40;
    int h = r / 10, t = r % 10;
    int which = g & 3, layer = g >> 2;
    const float* fc; const float* al; const float* ar;
    if (which == 0)      { fc = fc0; al = al0; ar = ar0; }
    else if (which == 1) { fc = fc1; al = al1; ar = ar1; }
    else if (which == 2) { fc = fc2; al = al2; ar = ar2; }
    else                 { fc = fc3; al = al3; ar = ar3; }
    fc += layer * (HH * DD * TT);
    al += layer * (HH * DD);
    ar += layer * (HH * DD);
    float vl = 0.f, vr = 0.f;
#pragma unroll
    for (int d = 0; d < DD; d++) {
        float w = fc[(h * DD + d) * TT + t];
        vl += al[h * DD + d] * w;
        vr += ar[h * DD + d] * w;
    }
    vbuf[g * 80 + r] = vl;
    vbuf[g * 80 + 40 + r] = vr;
}

// ---------------- fused dual-GAT: gather feat, attention, aggregate, W-apply ----
// Computes two GATs sharing the same graph. If SAMEF, fB is ignored (== fA).
// W layout (H*D, T) row-major; v = [vl(H,T) | vr(H,T)] per GAT slot.
// __launch_bounds__(256, 2): live state ~170 VGPRs (accA/accB 80 + feat regs);
// the default heuristic capped at 64 VGPRs and spilled ~800 MB/dispatch to
// scratch (round-2 counters: WRITE_SIZE 496 MB vs 26 MB legit).
template <bool STATS, bool SAMEF>
__global__ void __launch_bounds__(256, 2)
gat2_kernel(const float* __restrict__ fA, const float* __restrict__ fB,
            const float* __restrict__ WA, const float* __restrict__ WB,
            const float* __restrict__ vA, const float* __restrict__ vB,
            const int* __restrict__ off, const int* __restrict__ csr_src,
            float* __restrict__ gA, float* __restrict__ gB,
            float* __restrict__ stats) {
    __shared__ float sWA[HH * DD * TT], sWB[HH * DD * TT];
    __shared__ float svA[2 * HH * TT], svB[2 * HH * TT];
    for (int k = threadIdx.x; k < HH * DD * TT; k += blockDim.x) {
        sWA[k] = WA[k]; sWB[k] = WB[k];
    }
    for (int k = threadIdx.x; k < 2 * HH * TT; k += blockDim.x) {
        svA[k] = vA[k]; svB[k] = vB[k];
    }
    __syncthreads();

    int i = blockIdx.x * blockDim.x + threadIdx.x;
    float lsumA = 0.f, lsqA = 0.f, lsumB = 0.f, lsqB = 0.f;
    if (i < NB) {
        int n = i / BB, b = i % BB;
        int s0 = off[n], s1 = off[n + 1];

        // self features -> er per head for both GATs
        float fsA[TT], fsB[TT];
        const float* pA = fA + (size_t)i * TT;
#pragma unroll
        for (int t = 0; t < TT; t++) fsA[t] = pA[t];
        if (!SAMEF) {
            const float* pB = fB + (size_t)i * TT;
#pragma unroll
            for (int t = 0; t < TT; t++) fsB[t] = pB[t];
        }
        float erA[HH], erB[HH];
#pragma unroll
        for (int h = 0; h < HH; h++) {
            float ea = 0.f, eb = 0.f;
#pragma unroll
            for (int t = 0; t < TT; t++) {
                ea += svA[HH * TT + h * TT + t] * fsA[t];
                eb += svB[HH * TT + h * TT + t] * (SAMEF ? fsA[t] : fsB[t]);
            }
            erA[h] = ea; erB[h] = eb;
        }

        float denA[HH] = {0, 0, 0, 0}, denB[HH] = {0, 0, 0, 0};
        float accA[HH][TT], accB[HH][TT];
#pragma unroll
        for (int h = 0; h < HH; h++)
#pragma unroll
            for (int t = 0; t < TT; t++) { accA[h][t] = 0.f; accB[h][t] = 0.f; }

        for (int k = s0; k < s1; k++) {
            int s = csr_src[k];
            size_t sb = (size_t)s * BB + b;
            float fa[TT], fb[TT];
            const float* qa = fA + sb * TT;
#pragma unroll
            for (int t = 0; t < TT; t++) fa[t] = qa[t];
            if (!SAMEF) {
                const float* qb = fB + sb * TT;
#pragma unroll
                for (int t = 0; t < TT; t++) fb[t] = qb[t];
            }
#pragma unroll
            for (int h = 0; h < HH; h++) {
                float ela = 0.f, elb = 0.f;
#pragma unroll
                for (int t = 0; t < TT; t++) {
                    ela += svA[h * TT + t] * fa[t];
                    elb += svB[h * TT + t] * (SAMEF ? fa[t] : fb[t]);
                }
                float za = ela + erA[h];
                za = (za >= 0.f) ? za : NEG * za;
                float wa = __expf(za);
                denA[h] += wa;
                float zb = elb + erB[h];
                zb = (zb >= 0.f) ? zb : NEG * zb;
                float wb = __expf(zb);
                denB[h] += wb;
#pragma unroll
                for (int t = 0; t < TT; t++) {
                    accA[h][t] += wa * fa[t];
                    accB[h][t] += wb * (SAMEF ? fa[t] : fb[t]);
                }
            }
        }

        // apply W per head on the aggregated feat, leaky, mean over heads
        float outA[DD], outB[DD];
#pragma unroll
        for (int d = 0; d < DD; d++) { outA[d] = 0.f; outB[d] = 0.f; }
        bool nz = (s1 > s0);
#pragma unroll
        for (int h = 0; h < HH; h++) {
            float rdA = nz ? (1.0f / denA[h]) : 0.f;
            float rdB = nz ? (1.0f / denB[h]) : 0.f;
#pragma unroll
            for (int t = 0; t < TT; t++) { accA[h][t] *= rdA; accB[h][t] *= rdB; }
#pragma unroll
            for (int d = 0; d < DD; d++) {
                float va = 0.f, vb = 0.f;
#pragma unroll
                for (int t = 0; t < TT; t++) {
                    va += sWA[(h * DD + d) * TT + t] * accA[h][t];
                    vb += sWB[(h * DD + d) * TT + t] * accB[h][t];
                }
                va = (va >= 0.f) ? va : NEG * va;
                vb = (vb >= 0.f) ? vb : NEG * vb;
                outA[d] += va;
                outB[d] += vb;
            }
        }
        float* gpa = gA + (size_t)i * DD;
        float* gpb = gB + (size_t)i * DD;
#pragma unroll
        for (int d = 0; d < DD; d++) {
            float oa = outA[d] * 0.25f, ob = outB[d] * 0.25f;
            gpa[d] = oa; gpb[d] = ob;
            if (STATS) { lsumA += oa; lsqA += oa * oa; lsumB += ob; lsqB += ob * ob; }
        }
    }
    if (STATS) {
#pragma unroll
        for (int o = 32; o > 0; o >>= 1) {
            lsumA += __shfl_down(lsumA, o, 64);
            lsqA  += __shfl_down(lsqA, o, 64);
            lsumB += __shfl_down(lsumB, o, 64);
            lsqB  += __shfl_down(lsqB, o, 64);
        }
        __shared__ float ss[4][4];
        int wid = threadIdx.x >> 6, lid = threadIdx.x & 63;
        if (lid == 0) { ss[wid][0] = lsumA; ss[wid][1] = lsqA; ss[wid][2] = lsumB; ss[wid][3] = lsqB; }
        __syncthreads();
        if (threadIdx.x == 0) {
            float a0 = 0.f, a1 = 0.f, a2 = 0.f, a3 = 0.f;
#pragma unroll
            for (int w = 0; w < 4; w++) { a0 += ss[w][0]; a1 += ss[w][1]; a2 += ss[w][2]; a3 += ss[w][3]; }
            atomicAdd(&stats[0], a0);
            atomicAdd(&stats[1], a1);
            atomicAdd(&stats[2], a2);
            atomicAdd(&stats[3], a3);
        }
    }
}

// ---------------- LN(A), LN(B), average ----------------
__global__ void lncomb_kernel(const float* __restrict__ ga, const float* __restrict__ gb,
                              const float* __restrict__ stats, float* __restrict__ h) {
    int i = blockIdx.x * blockDim.x + threadIdx.x;
    if (i >= NBT) return;
    const float M = (float)NBT;
    float ma = stats[0] / M; float va = stats[1] / M - ma * ma;
    float mb = stats[2] / M; float vb = stats[3] / M - mb * mb;
    float ra = rsqrtf(va + 1e-5f), rb = rsqrtf(vb + 1e-5f);
    h[i] = 0.5f * ((ga[i] - ma) * ra + (gb[i] - mb) * rb);
}

// ---------------- final combine ----------------
__global__ void outcomb_kernel(const float* __restrict__ reg, const float* __restrict__ ga,
                               const float* __restrict__ gb, float* __restrict__ out) {
    int i = blockIdx.x * blockDim.x + threadIdx.x;
    if (i >= NBT) return;
    int nb = i / DD;
    out[i] = (reg[nb] + ga[i] + gb[i]) * (1.0f / 3.0f);
}

extern "C" void kernel_launch(void* const* d_in, const int* in_sizes, int n_in,
                              void* d_out, int out_size, void* d_ws, size_t ws_size,
                              hipStream_t stream) {
    const float* x      = (const float*)d_in[0];
    const int* ps_src   = (const int*)d_in[1];
    const int* ps_dst   = (const int*)d_in[2];
    const int* rl_src   = (const int*)d_in[3];
    const int* rl_dst   = (const int*)d_in[4];
    const float* mu_p_fc = (const float*)d_in[5];
    const float* mu_p_al = (const float*)d_in[6];
    const float* mu_p_ar = (const float*)d_in[7];
    const float* sg_p_fc = (const float*)d_in[8];
    const float* sg_p_al = (const float*)d_in[9];
    const float* sg_p_ar = (const float*)d_in[10];
    const float* mu_r_fc = (const float*)d_in[11];
    const float* mu_r_al = (const float*)d_in[12];
    const float* mu_r_ar = (const float*)d_in[13];
    const float* sg_r_fc = (const float*)d_in[14];
    const float* sg_r_al = (const float*)d_in[15];
    const float* sg_r_ar = (const float*)d_in[16];
    const float* reg_mu_w = (const float*)d_in[17];
    const float* reg_mu_b = (const float*)d_in[18];
    const float* reg_sg_w = (const float*)d_in[19];
    const float* reg_sg_b = (const float*)d_in[20];

    float* out = (float*)d_out;

    // ---- workspace carve ----
    float* fw = (float*)d_ws;
    float* mu    = fw;              fw += NBT;
    float* sigma = fw;              fw += NBT;
    float* gA    = fw;              fw += NBT;   // mu-path scratch / mu_pf
    float* gB    = fw;              fw += NBT;   // sg-path scratch / sg_pf
    float* gA2   = fw;              fw += NBT;   // mu_rf
    float* gB2   = fw;              fw += NBT;   // sg_rf
    float* hp    = fw;              fw += NBT;
    float* hrl   = fw;              fw += NBT;
    float* regmu = fw;              fw += NB;
    float* regsg = fw;              fw += NB;
    float* vbuf  = fw;              fw += 8 * 80;
    int* iw = (int*)fw;
    int* ps_off = iw;               iw += NN + 1;
    int* rl_off = iw;               iw += NN + 1;
    int* ps_csr = iw;               iw += EE;
    int* rl_csr = iw;               iw += EE;
    // zero region starts here:
    int* deg_ps = iw;               iw += NN;
    int* cur_ps = iw;               iw += NN;
    int* deg_rl = iw;               iw += NN;
    int* cur_rl = iw;               iw += NN;
    float* stats = (float*)iw;      // 8 floats
    size_t zero_bytes = (size_t)(4 * NN) * sizeof(int) + 8 * sizeof(float);
    hipMemsetAsync(deg_ps, 0, zero_bytes, stream);

    const int TPB = 256;
    const int GRID_NB  = (NB + TPB - 1) / TPB;
    const int GRID_NBT = (NBT + TPB - 1) / TPB;
    const int GRID_E   = (EE + TPB - 1) / TPB;

    extract_kernel<<<GRID_NB, TPB, 0, stream>>>(x, reg_mu_w, reg_mu_b, reg_sg_w, reg_sg_b,
                                                mu, sigma, regmu, regsg);

    // CSR for both graphs
    deg_kernel<<<GRID_E, TPB, 0, stream>>>(ps_dst, deg_ps);
    deg_kernel<<<GRID_E, TPB, 0, stream>>>(rl_dst, deg_rl);
    scan_kernel<<<1, 1024, 0, stream>>>(deg_ps, ps_off);
    scan_kernel<<<1, 1024, 0, stream>>>(deg_rl, rl_off);
    fill_kernel<<<GRID_E, TPB, 0, stream>>>(ps_src, ps_dst, ps_off, cur_ps, ps_csr);
    fill_kernel<<<GRID_E, TPB, 0, stream>>>(rl_src, rl_dst, rl_off, cur_rl, rl_csr);

    // vl/vr precompute for all 8 GAT slots
    vpre_kernel<<<1, 320, 0, stream>>>(mu_p_fc, mu_p_al, mu_p_ar,
                                       sg_p_fc, sg_p_al, sg_p_ar,
                                       mu_r_fc, mu_r_al, mu_r_ar,
                                       sg_r_fc, sg_r_al, sg_r_ar, vbuf);

    // slots: 0 mu_p L0, 1 sg_p L0, 2 mu_r L0, 3 sg_r L0, 4 mu_p L1, 5 sg_p L1, 6 mu_r L1, 7 sg_r L1
    // ---- layer 0 (two fused dual-GATs) ----
    gat2_kernel<true, false><<<GRID_NB, TPB, 0, stream>>>(
        mu, sigma, mu_p_fc, sg_p_fc, vbuf + 0 * 80, vbuf + 1 * 80,
        ps_off, ps_csr, gA, gB, stats + 0);
    gat2_kernel<true, false><<<GRID_NB, TPB, 0, stream>>>(
        mu, sigma, mu_r_fc, sg_r_fc, vbuf + 2 * 80, vbuf + 3 * 80,
        rl_off, rl_csr, gA2, gB2, stats + 4);
    lncomb_kernel<<<GRID_NBT, TPB, 0, stream>>>(gA, gB, stats + 0, hp);
    lncomb_kernel<<<GRID_NBT, TPB, 0, stream>>>(gA2, gB2, stats + 4, hrl);

    // ---- final layers (two fused dual-GATs, shared feat) ----
    gat2_kernel<false, true><<<GRID_NB, TPB, 0, stream>>>(
        hp, nullptr, mu_p_fc + 400, sg_p_fc + 400, vbuf + 4 * 80, vbuf + 5 * 80,
        ps_off, ps_csr, gA, gB, nullptr);
    gat2_kernel<false, true><<<GRID_NB, TPB, 0, stream>>>(
        hrl, nullptr, mu_r_fc + 400, sg_r_fc + 400, vbuf + 6 * 80, vbuf + 7 * 80,
        rl_off, rl_csr, gA2, gB2, nullptr);

    outcomb_kernel<<<GRID_NBT, TPB, 0, stream>>>(regmu, gA, gA2, out);
    outcomb_kernel<<<GRID_NBT, TPB, 0, stream>>>(regsg, gB, gB2, out + NBT);
}

// Round 4
// 855.724 us; speedup vs baseline: 1.7592x; 1.7592x over previous
//
#include <hip/hip_runtime.h>

#define NN 10000
#define BB 32
#define EE 40000
#define HH 4
#define DD 10
#define TT 10
#define NEG 0.2f

#define NB   (NN*BB)          // 320000
#define NBH_T (NB*HH)         // 1280000 threads for gat kernels
#define NBT  (NN*BB*TT)       // 3200000

// ---------------- extract mu/sigma + regression heads ----------------
__global__ void extract_kernel(const float* __restrict__ x,
                               const float* __restrict__ wmu, const float* __restrict__ bmu,
                               const float* __restrict__ wsg, const float* __restrict__ bsg,
                               float* __restrict__ mu, float* __restrict__ sg,
                               float* __restrict__ regmu, float* __restrict__ regsg) {
    int i = blockIdx.x * blockDim.x + threadIdx.x;   // over N*B
    if (i >= NB) return;
    int n = i / BB, b = i % BB;
    float smu = 0.f, ssg = 0.f;
    float muv[TT], sgv[TT];
#pragma unroll
    for (int t = 0; t < TT; t++) {
        size_t xi = (((size_t)t * NN + n) * BB + b) * 3;
        float m = x[xi], s = x[xi + 1];
        muv[t] = m; sgv[t] = s;
        smu += m * wmu[t];
        ssg += s * wsg[t];
    }
#pragma unroll
    for (int t = 0; t < TT; t++) {
        mu[(size_t)i * TT + t] = muv[t];
        sg[(size_t)i * TT + t] = sgv[t];
    }
    regmu[i] = smu + bmu[0];
    regsg[i] = ssg + bsg[0];
}

// ---------------- CSR build ----------------
__global__ void deg_kernel(const int* __restrict__ dst, int* __restrict__ deg) {
    int e = blockIdx.x * blockDim.x + threadIdx.x;
    if (e < EE) atomicAdd(&deg[dst[e]], 1);
}

__global__ void scan_kernel(const int* __restrict__ deg, int* __restrict__ off) {
    __shared__ int sm[1024];
    __shared__ int carry_s;
    if (threadIdx.x == 0) { carry_s = 0; off[0] = 0; }
    __syncthreads();
    for (int base = 0; base < NN; base += 1024) {
        int i = base + (int)threadIdx.x;
        int v = (i < NN) ? deg[i] : 0;
        sm[threadIdx.x] = v;
        __syncthreads();
        for (int s = 1; s < 1024; s <<= 1) {
            int t = (threadIdx.x >= (unsigned)s) ? sm[threadIdx.x - s] : 0;
            __syncthreads();
            sm[threadIdx.x] += t;
            __syncthreads();
        }
        if (i < NN) off[i + 1] = carry_s + sm[threadIdx.x];
        __syncthreads();
        if (threadIdx.x == 0) carry_s += sm[1023];
        __syncthreads();
    }
}

__global__ void fill_kernel(const int* __restrict__ src, const int* __restrict__ dst,
                            const int* __restrict__ off, int* __restrict__ cursor,
                            int* __restrict__ csr_src) {
    int e = blockIdx.x * blockDim.x + threadIdx.x;
    if (e < EE) {
        int d = dst[e];
        int p = atomicAdd(&cursor[d], 1);
        csr_src[off[d] + p] = src[e];
    }
}

// ---------------- precompute vl/vr for all 8 GATs ----------------
// vbuf layout: 8 slots of [vl(H*T=40) | vr(40)];
// slot g: which = g&3 in {mu_p, sg_p, mu_r, sg_r}, layer = g>>2
__global__ void vpre_kernel(const float* __restrict__ fc0, const float* __restrict__ al0, const float* __restrict__ ar0,
                            const float* __restrict__ fc1, const float* __restrict__ al1, const float* __restrict__ ar1,
                            const float* __restrict__ fc2, const float* __restrict__ al2, const float* __restrict__ ar2,
                            const float* __restrict__ fc3, const float* __restrict__ al3, const float* __restrict__ ar3,
                            float* __restrict__ vbuf) {
    int j = threadIdx.x;                 // 0..319
    if (j >= 320) return;
    int g = j / 40, r = j % 40;
    int h = r / 10, t = r % 10;
    int which = g & 3, layer = g >> 2;
    const float* fc; const float* al; const float* ar;
    if (which == 0)      { fc = fc0; al = al0; ar = ar0; }
    else if (which == 1) { fc = fc1; al = al1; ar = ar1; }
    else if (which == 2) { fc = fc2; al = al2; ar = ar2; }
    else                 { fc = fc3; al = al3; ar = ar3; }
    fc += layer * (HH * DD * TT);
    al += layer * (HH * DD);
    ar += layer * (HH * DD);
    float vl = 0.f, vr = 0.f;
#pragma unroll
    for (int d = 0; d < DD; d++) {
        float w = fc[(h * DD + d) * TT + t];
        vl += al[h * DD + d] * w;
        vr += ar[h * DD + d] * w;
    }
    vbuf[g * 80 + r] = vl;
    vbuf[g * 80 + 40 + r] = vr;
}

// ---------------- fused dual-GAT, thread per (node, batch, head) ----------------
// Live state per lane ~75 floats (round-3's per-(n,b) version needed ~170 and
// the allocator spilled at both 64 and 128 VGPR caps -> 0.5-0.7 GB scratch
// traffic per dispatch). Head-mean via __shfl_xor over the 4 adjacent lanes.
// Wave layout: i = (nb<<2)|h; a 64-lane wave = 16 consecutive nb x 4 heads,
// all within one node n (blocks of 64 never cross a node since BB*HH=128
// divides 256), so the edge loop is wave-uniform.
template <bool STATS, bool SAMEF>
__global__ void gat2_kernel(const float* __restrict__ fA, const float* __restrict__ fB,
                            const float* __restrict__ WA, const float* __restrict__ WB,
                            const float* __restrict__ vA, const float* __restrict__ vB,
                            const int* __restrict__ off, const int* __restrict__ csr_src,
                            float* __restrict__ gA, float* __restrict__ gB,
                            float* __restrict__ stats) {
    __shared__ float sWA[HH * DD * TT], sWB[HH * DD * TT];
    for (int k = threadIdx.x; k < HH * DD * TT; k += blockDim.x) {
        sWA[k] = WA[k]; sWB[k] = WB[k];
    }
    __syncthreads();

    int i = blockIdx.x * blockDim.x + threadIdx.x;   // over NB*HH
    float lsumA = 0.f, lsqA = 0.f, lsumB = 0.f, lsqB = 0.f;
    if (i < NBH_T) {
        int h  = i & 3;
        int nb = i >> 2;          // n*32 + b
        int b  = nb & 31;
        int n  = nb >> 5;
        int s0 = off[n], s1 = off[n + 1];

        // per-lane attention vectors for this head
        float vlA[TT], vlB[TT];
#pragma unroll
        for (int t = 0; t < TT; t++) {
            vlA[t] = vA[h * TT + t];
            vlB[t] = vB[h * TT + t];
        }
        // er from self features (fs dead after this)
        float erA = 0.f, erB = 0.f;
        {
            const float* pA = fA + (size_t)nb * TT;
            const float* pB = SAMEF ? pA : (fB + (size_t)nb * TT);
#pragma unroll
            for (int t = 0; t < TT; t++) {
                float fsa = pA[t];
                float fsb = SAMEF ? fsa : pB[t];
                erA += vA[HH * TT + h * TT + t] * fsa;
                erB += vB[HH * TT + h * TT + t] * fsb;
            }
        }

        float accA[TT], accB[TT];
#pragma unroll
        for (int t = 0; t < TT; t++) { accA[t] = 0.f; accB[t] = 0.f; }
        float denA = 0.f, denB = 0.f;

        for (int k = s0; k < s1; k++) {
            int s = csr_src[k];
            size_t sb = (size_t)(s * BB + b) * TT;
            float fa[TT];
            const float* qa = fA + sb;
#pragma unroll
            for (int t = 0; t < TT; t++) fa[t] = qa[t];
            float fb[TT];
            if (!SAMEF) {
                const float* qb = fB + sb;
#pragma unroll
                for (int t = 0; t < TT; t++) fb[t] = qb[t];
            }
            float ela = 0.f, elb = 0.f;
#pragma unroll
            for (int t = 0; t < TT; t++) {
                ela += vlA[t] * fa[t];
                elb += vlB[t] * (SAMEF ? fa[t] : fb[t]);
            }
            float za = ela + erA;
            za = (za >= 0.f) ? za : NEG * za;
            float wa = __expf(za);
            denA += wa;
            float zb = elb + erB;
            zb = (zb >= 0.f) ? zb : NEG * zb;
            float wb = __expf(zb);
            denB += wb;
#pragma unroll
            for (int t = 0; t < TT; t++) {
                accA[t] += wa * fa[t];
                accB[t] += wb * (SAMEF ? fa[t] : fb[t]);
            }
        }

        bool nz = (s1 > s0);
        float rdA = nz ? (1.0f / denA) : 0.f;
        float rdB = nz ? (1.0f / denB) : 0.f;

        // W_h on aggregated feat, leaky, then mean over heads via shfl_xor
        float outA[DD], outB[DD];
#pragma unroll
        for (int d = 0; d < DD; d++) {
            float va = 0.f, vb = 0.f;
#pragma unroll
            for (int t = 0; t < TT; t++) {
                va += sWA[(h * DD + d) * TT + t] * accA[t];
                vb += sWB[(h * DD + d) * TT + t] * accB[t];
            }
            va *= rdA; vb *= rdB;
            va = (va >= 0.f) ? va : NEG * va;
            vb = (vb >= 0.f) ? vb : NEG * vb;
            outA[d] = va * 0.25f;
            outB[d] = vb * 0.25f;
        }
#pragma unroll
        for (int d = 0; d < DD; d++) {
            outA[d] += __shfl_xor(outA[d], 1, 64);
            outA[d] += __shfl_xor(outA[d], 2, 64);
            outB[d] += __shfl_xor(outB[d], 1, 64);
            outB[d] += __shfl_xor(outB[d], 2, 64);
        }
        if (h == 0) {
            float* gpa = gA + (size_t)nb * DD;
            float* gpb = gB + (size_t)nb * DD;
#pragma unroll
            for (int d = 0; d < DD; d++) {
                float oa = outA[d], ob = outB[d];
                gpa[d] = oa; gpb[d] = ob;
                if (STATS) { lsumA += oa; lsqA += oa * oa; lsumB += ob; lsqB += ob * ob; }
            }
        }
    }
    if (STATS) {
#pragma unroll
        for (int o = 32; o > 0; o >>= 1) {
            lsumA += __shfl_down(lsumA, o, 64);
            lsqA  += __shfl_down(lsqA, o, 64);
            lsumB += __shfl_down(lsumB, o, 64);
            lsqB  += __shfl_down(lsqB, o, 64);
        }
        __shared__ float ss[4][4];
        int wid = threadIdx.x >> 6, lid = threadIdx.x & 63;
        if (lid == 0) { ss[wid][0] = lsumA; ss[wid][1] = lsqA; ss[wid][2] = lsumB; ss[wid][3] = lsqB; }
        __syncthreads();
        if (threadIdx.x == 0) {
            float a0 = 0.f, a1 = 0.f, a2 = 0.f, a3 = 0.f;
#pragma unroll
            for (int w = 0; w < 4; w++) { a0 += ss[w][0]; a1 += ss[w][1]; a2 += ss[w][2]; a3 += ss[w][3]; }
            atomicAdd(&stats[0], a0);
            atomicAdd(&stats[1], a1);
            atomicAdd(&stats[2], a2);
            atomicAdd(&stats[3], a3);
        }
    }
}

// ---------------- LN(A), LN(B), average ----------------
__global__ void lncomb_kernel(const float* __restrict__ ga, const float* __restrict__ gb,
                              const float* __restrict__ stats, float* __restrict__ h) {
    int i = blockIdx.x * blockDim.x + threadIdx.x;
    if (i >= NBT) return;
    const float M = (float)NBT;
    float ma = stats[0] / M; float va = stats[1] / M - ma * ma;
    float mb = stats[2] / M; float vb = stats[3] / M - mb * mb;
    float ra = rsqrtf(va + 1e-5f), rb = rsqrtf(vb + 1e-5f);
    h[i] = 0.5f * ((ga[i] - ma) * ra + (gb[i] - mb) * rb);
}

// ---------------- final combine ----------------
__global__ void outcomb_kernel(const float* __restrict__ reg, const float* __restrict__ ga,
                               const float* __restrict__ gb, float* __restrict__ out) {
    int i = blockIdx.x * blockDim.x + threadIdx.x;
    if (i >= NBT) return;
    int nb = i / DD;
    out[i] = (reg[nb] + ga[i] + gb[i]) * (1.0f / 3.0f);
}

extern "C" void kernel_launch(void* const* d_in, const int* in_sizes, int n_in,
                              void* d_out, int out_size, void* d_ws, size_t ws_size,
                              hipStream_t stream) {
    const float* x      = (const float*)d_in[0];
    const int* ps_src   = (const int*)d_in[1];
    const int* ps_dst   = (const int*)d_in[2];
    const int* rl_src   = (const int*)d_in[3];
    const int* rl_dst   = (const int*)d_in[4];
    const float* mu_p_fc = (const float*)d_in[5];
    const float* mu_p_al = (const float*)d_in[6];
    const float* mu_p_ar = (const float*)d_in[7];
    const float* sg_p_fc = (const float*)d_in[8];
    const float* sg_p_al = (const float*)d_in[9];
    const float* sg_p_ar = (const float*)d_in[10];
    const float* mu_r_fc = (const float*)d_in[11];
    const float* mu_r_al = (const float*)d_in[12];
    const float* mu_r_ar = (const float*)d_in[13];
    const float* sg_r_fc = (const float*)d_in[14];
    const float* sg_r_al = (const float*)d_in[15];
    const float* sg_r_ar = (const float*)d_in[16];
    const float* reg_mu_w = (const float*)d_in[17];
    const float* reg_mu_b = (const float*)d_in[18];
    const float* reg_sg_w = (const float*)d_in[19];
    const float* reg_sg_b = (const float*)d_in[20];

    float* out = (float*)d_out;

    // ---- workspace carve ----
    float* fw = (float*)d_ws;
    float* mu    = fw;              fw += NBT;
    float* sigma = fw;              fw += NBT;
    float* gA    = fw;              fw += NBT;   // mu-path scratch / mu_pf
    float* gB    = fw;              fw += NBT;   // sg-path scratch / sg_pf
    float* gA2   = fw;              fw += NBT;   // mu_rf
    float* gB2   = fw;              fw += NBT;   // sg_rf
    float* hp    = fw;              fw += NBT;
    float* hrl   = fw;              fw += NBT;
    float* regmu = fw;              fw += NB;
    float* regsg = fw;              fw += NB;
    float* vbuf  = fw;              fw += 8 * 80;
    int* iw = (int*)fw;
    int* ps_off = iw;               iw += NN + 1;
    int* rl_off = iw;               iw += NN + 1;
    int* ps_csr = iw;               iw += EE;
    int* rl_csr = iw;               iw += EE;
    // zero region starts here:
    int* deg_ps = iw;               iw += NN;
    int* cur_ps = iw;               iw += NN;
    int* deg_rl = iw;               iw += NN;
    int* cur_rl = iw;               iw += NN;
    float* stats = (float*)iw;      // 8 floats
    size_t zero_bytes = (size_t)(4 * NN) * sizeof(int) + 8 * sizeof(float);
    hipMemsetAsync(deg_ps, 0, zero_bytes, stream);

    const int TPB = 256;
    const int GRID_NB  = (NB + TPB - 1) / TPB;
    const int GRID_NBH = (NBH_T + TPB - 1) / TPB;
    const int GRID_NBT = (NBT + TPB - 1) / TPB;
    const int GRID_E   = (EE + TPB - 1) / TPB;

    extract_kernel<<<GRID_NB, TPB, 0, stream>>>(x, reg_mu_w, reg_mu_b, reg_sg_w, reg_sg_b,
                                                mu, sigma, regmu, regsg);

    // CSR for both graphs
    deg_kernel<<<GRID_E, TPB, 0, stream>>>(ps_dst, deg_ps);
    deg_kernel<<<GRID_E, TPB, 0, stream>>>(rl_dst, deg_rl);
    scan_kernel<<<1, 1024, 0, stream>>>(deg_ps, ps_off);
    scan_kernel<<<1, 1024, 0, stream>>>(deg_rl, rl_off);
    fill_kernel<<<GRID_E, TPB, 0, stream>>>(ps_src, ps_dst, ps_off, cur_ps, ps_csr);
    fill_kernel<<<GRID_E, TPB, 0, stream>>>(rl_src, rl_dst, rl_off, cur_rl, rl_csr);

    // vl/vr precompute for all 8 GAT slots
    vpre_kernel<<<1, 320, 0, stream>>>(mu_p_fc, mu_p_al, mu_p_ar,
                                       sg_p_fc, sg_p_al, sg_p_ar,
                                       mu_r_fc, mu_r_al, mu_r_ar,
                                       sg_r_fc, sg_r_al, sg_r_ar, vbuf);

    // slots: 0 mu_p L0, 1 sg_p L0, 2 mu_r L0, 3 sg_r L0, 4 mu_p L1, 5 sg_p L1, 6 mu_r L1, 7 sg_r L1
    // ---- layer 0 (two fused dual-GATs) ----
    gat2_kernel<true, false><<<GRID_NBH, TPB, 0, stream>>>(
        mu, sigma, mu_p_fc, sg_p_fc, vbuf + 0 * 80, vbuf + 1 * 80,
        ps_off, ps_csr, gA, gB, stats + 0);
    gat2_kernel<true, false><<<GRID_NBH, TPB, 0, stream>>>(
        mu, sigma, mu_r_fc, sg_r_fc, vbuf + 2 * 80, vbuf + 3 * 80,
        rl_off, rl_csr, gA2, gB2, stats + 4);
    lncomb_kernel<<<GRID_NBT, TPB, 0, stream>>>(gA, gB, stats + 0, hp);
    lncomb_kernel<<<GRID_NBT, TPB, 0, stream>>>(gA2, gB2, stats + 4, hrl);

    // ---- final layers (two fused dual-GATs, shared feat) ----
    gat2_kernel<false, true><<<GRID_NBH, TPB, 0, stream>>>(
        hp, nullptr, mu_p_fc + 400, sg_p_fc + 400, vbuf + 4 * 80, vbuf + 5 * 80,
        ps_off, ps_csr, gA, gB, nullptr);
    gat2_kernel<false, true><<<GRID_NBH, TPB, 0, stream>>>(
        hrl, nullptr, mu_r_fc + 400, sg_r_fc + 400, vbuf + 6 * 80, vbuf + 7 * 80,
        rl_off, rl_csr, gA2, gB2, nullptr);

    outcomb_kernel<<<GRID_NBT, TPB, 0, stream>>>(regmu, gA, gA2, out);
    outcomb_kernel<<<GRID_NBT, TPB, 0, stream>>>(regsg, gB, gB2, out + NBT);
}